// Round 11
// baseline (151.809 us; speedup 1.0000x reference)
//
#include <hip/hip_runtime.h>
#include <hip/hip_bf16.h>
#include <hip/hip_cooperative_groups.h>

namespace cg = cooperative_groups;

#define NN 10000
#define NE 640000
#define D_IN 128
#define D_H 128
#define N_CLS 64
#define CAP 160    // per-node capacity (ushort): mean 64 sigma 8 -> +12 sigma
#define GRP 157    // coarse groups: dst>>6 (64 nodes/group)
#define CAPC 4800  // per-group coarse capacity
#define CCS 16     // coarse_cnt stride (ints): one counter per 64B line
#define SENT 10000 // sentinel node id (zero row)

// fallback (round-9, proven) params
#define F_EPB 1024
#define F_AB 625    // 625*1024 == 640000
#define F_CB 1251   // (NN+1)*32 uint2 / 256
#define F_WB 80     // (8192+8192+4096)/256

// cooperative params
#define C_NB 768    // 3 blocks/CU needed; launch_bounds allows 4 -> margin
#define C_T 256
#define C_EPB 834   // ceil(NE / C_NB)
#define C_SL 4      // P2 slices per group: 157*4 = 628 <= 768
#define C_NPI 3072  // nodes per layer iteration: C_NB*4

// ---- bf16 helpers ----
__device__ __forceinline__ float blo(unsigned u) { return __uint_as_float(u << 16); }
__device__ __forceinline__ float bhi(unsigned u) { return __uint_as_float(u & 0xffff0000u); }
__device__ __forceinline__ unsigned short f2bf(float f) {
    unsigned u = __float_as_uint(f);
    return (unsigned short)((u + 0x7fffu + ((u >> 16) & 1u)) >> 16);
}
__device__ __forceinline__ unsigned packbf(float a, float b) {
    return (unsigned)f2bf(a) | ((unsigned)f2bf(b) << 16);
}

// ======================= FALLBACK PATH (round-9, proven) =======================

__global__ __launch_bounds__(256) void prep_a(const int* __restrict__ src,
                                              const int* __restrict__ dst,
                                              int* __restrict__ coarse_cnt,
                                              unsigned* __restrict__ coarse,
                                              const float* __restrict__ feat,
                                              unsigned* __restrict__ hb0,
                                              const float* __restrict__ W0,
                                              const float* __restrict__ W1,
                                              const float* __restrict__ W2,
                                              unsigned* __restrict__ wb0,
                                              unsigned* __restrict__ wb1,
                                              unsigned* __restrict__ wb2) {
    int bid = blockIdx.x;
    if (bid >= F_AB + F_CB) {   // ---- W pack ----
        int t = (bid - F_AB - F_CB) * 256 + threadIdx.x;
        if (t < 8192) {
            int kp = t >> 7, j = t & 127;
            wb0[t] = packbf(W0[(2 * kp) * 128 + j], W0[(2 * kp + 1) * 128 + j]);
        } else if (t < 16384) {
            int tt = t - 8192, kp = tt >> 7, j = tt & 127;
            wb1[tt] = packbf(W1[(2 * kp) * 128 + j], W1[(2 * kp + 1) * 128 + j]);
        } else if (t < 20480) {
            int tt = t - 16384, kp = tt >> 6, j = tt & 63;
            wb2[tt] = packbf(W2[(2 * kp) * 64 + j], W2[(2 * kp + 1) * 64 + j]);
        }
        return;
    }
    if (bid >= F_AB) {   // ---- feature conv ----
        int t = (bid - F_AB) * 256 + threadIdx.x;
        if (t < NN * 32) {
            float4 f = ((const float4*)feat)[t];
            ((uint2*)hb0)[t] = make_uint2(packbf(f.x, f.y), packbf(f.z, f.w));
        } else if (t < (NN + 1) * 32) {
            ((uint2*)hb0)[t] = make_uint2(0u, 0u);
        }
        return;
    }
    __shared__ unsigned stage[F_EPB];
    __shared__ int hist[GRP], gbase[GRP], cur[GRP];
    const int t = threadIdx.x;
    for (int i = t; i < GRP; i += 256) hist[i] = 0;
    __syncthreads();
    const int e0 = bid * F_EPB;
    for (int i = t; i < F_EPB; i += 256) {
        int s = src[e0 + i];
        int d = dst[e0 + i];
        stage[i] = (unsigned)s | ((unsigned)d << 16);
        atomicAdd(&hist[d >> 6], 1);
    }
    __syncthreads();
    for (int i = t; i < GRP; i += 256) {
        gbase[i] = atomicAdd(&coarse_cnt[i * CCS], hist[i]);
        cur[i] = 0;
    }
    __syncthreads();
    for (int i = t; i < F_EPB; i += 256) {
        unsigned u = stage[i];
        int g = u >> 22;
        int r = atomicAdd(&cur[g], 1);
        coarse[g * CAPC + gbase[g] + r] = u;
    }
}

__global__ __launch_bounds__(1024) void prep_b(const int* __restrict__ coarse_cnt,
                                               const unsigned* __restrict__ coarse,
                                               int* __restrict__ cnt,
                                               unsigned short* __restrict__ colbuf) {
    __shared__ int cur[64];
    const int g = blockIdx.x;
    const int t = threadIdx.x;
    if (t < 64) cur[t] = 0;
    __syncthreads();
    const int m = coarse_cnt[g * CCS];
    const unsigned* cb = coarse + g * CAPC;
    for (int i = t; i < m; i += 1024) {
        unsigned u = cb[i];
        int s = (int)(u & 0xFFFFu);
        int d = (int)(u >> 16);
        int r = atomicAdd(&cur[d - (g << 6)], 1);
        colbuf[d * CAP + r] = (unsigned short)s;
    }
    __syncthreads();
    if (t < 64) {
        int n = (g << 6) + t;
        if (n < NN) {
            int c = cur[t];
            int pad = (16 - (c & 15)) & 15;
            unsigned short* base = colbuf + n * CAP;
            for (int k = 0; k < pad; ++k) base[c + k] = (unsigned short)SENT;
            cnt[n] = c + pad;
        }
    }
}

template <int J, bool LAST>
__global__ __launch_bounds__(256, 8) void gin_layer(const uint4* __restrict__ hb4,
                                                    const int* __restrict__ cnt,
                                                    const unsigned short* __restrict__ colbuf,
                                                    const unsigned* __restrict__ Wb,
                                                    unsigned short* __restrict__ outb,
                                                    float* __restrict__ outf) {
    constexpr int M = 4;
    __shared__ float xs[M][D_H];
    const int base = blockIdx.x * M;
    const int tid = threadIdx.x;
    const int wave = tid >> 6;
    const int lane = tid & 63;
    const int sub = lane >> 4;
    const int off = lane & 15;

    const int n = base + wave;
    float a0, a1, a2, a3, a4, a5, a6, a7;
    if (sub == 0) {
        uint4 u = hb4[n * 16 + off];
        a0 = blo(u.x); a1 = bhi(u.x); a2 = blo(u.y); a3 = bhi(u.y);
        a4 = blo(u.z); a5 = bhi(u.z); a6 = blo(u.w); a7 = bhi(u.w);
    } else {
        a0 = a1 = a2 = a3 = a4 = a5 = a6 = a7 = 0.f;
    }
    const int G4 = cnt[n] >> 2;
    const uint2* cl8 = (const uint2*)(colbuf + n * CAP);
    for (int g = 0; g < G4; g += 4) {
        uint2 p0 = cl8[g + 0];
        uint2 p1 = cl8[g + 1];
        uint2 p2 = cl8[g + 2];
        uint2 p3 = cl8[g + 3];
        unsigned w0 = (sub & 2) ? p0.y : p0.x;
        unsigned w1 = (sub & 2) ? p1.y : p1.x;
        unsigned w2 = (sub & 2) ? p2.y : p2.x;
        unsigned w3 = (sub & 2) ? p3.y : p3.x;
        int s0 = (sub & 1) ? (w0 >> 16) : (w0 & 0xffffu);
        int s1 = (sub & 1) ? (w1 >> 16) : (w1 & 0xffffu);
        int s2 = (sub & 1) ? (w2 >> 16) : (w2 & 0xffffu);
        int s3 = (sub & 1) ? (w3 >> 16) : (w3 & 0xffffu);
        uint4 uA = hb4[s0 * 16 + off];
        uint4 uB = hb4[s1 * 16 + off];
        uint4 uC = hb4[s2 * 16 + off];
        uint4 uD = hb4[s3 * 16 + off];
        a0 += (blo(uA.x) + blo(uB.x)) + (blo(uC.x) + blo(uD.x));
        a1 += (bhi(uA.x) + bhi(uB.x)) + (bhi(uC.x) + bhi(uD.x));
        a2 += (blo(uA.y) + blo(uB.y)) + (blo(uC.y) + blo(uD.y));
        a3 += (bhi(uA.y) + bhi(uB.y)) + (bhi(uC.y) + bhi(uD.y));
        a4 += (blo(uA.z) + blo(uB.z)) + (blo(uC.z) + blo(uD.z));
        a5 += (bhi(uA.z) + bhi(uB.z)) + (bhi(uC.z) + bhi(uD.z));
        a6 += (blo(uA.w) + blo(uB.w)) + (blo(uC.w) + blo(uD.w));
        a7 += (bhi(uA.w) + bhi(uB.w)) + (bhi(uC.w) + bhi(uD.w));
    }
    a0 += __shfl_xor(a0, 16); a0 += __shfl_xor(a0, 32);
    a1 += __shfl_xor(a1, 16); a1 += __shfl_xor(a1, 32);
    a2 += __shfl_xor(a2, 16); a2 += __shfl_xor(a2, 32);
    a3 += __shfl_xor(a3, 16); a3 += __shfl_xor(a3, 32);
    a4 += __shfl_xor(a4, 16); a4 += __shfl_xor(a4, 32);
    a5 += __shfl_xor(a5, 16); a5 += __shfl_xor(a5, 32);
    a6 += __shfl_xor(a6, 16); a6 += __shfl_xor(a6, 32);
    a7 += __shfl_xor(a7, 16); a7 += __shfl_xor(a7, 32);
    if (sub == 0) {
        *(float4*)&xs[wave][8 * off]     = make_float4(a0, a1, a2, a3);
        *(float4*)&xs[wave][8 * off + 4] = make_float4(a4, a5, a6, a7);
    }
    __syncthreads();

    constexpr int G = 256 / J;
    constexpr int NM = M / G;
    const int gq = tid / J;
    const int j = tid % J;
    const int mbase = gq * NM;
    float acc[NM];
#pragma unroll
    for (int m = 0; m < NM; ++m) acc[m] = 0.f;
    for (int k = 0; k < D_H; k += 4) {
        unsigned wp0 = Wb[(k >> 1) * J + j];
        unsigned wp1 = Wb[((k >> 1) + 1) * J + j];
        float w0 = blo(wp0), w1 = bhi(wp0), w2 = blo(wp1), w3 = bhi(wp1);
#pragma unroll
        for (int m = 0; m < NM; ++m) {
            float4 xv = *(const float4*)&xs[mbase + m][k];
            acc[m] += xv.x * w0 + xv.y * w1 + xv.z * w2 + xv.w * w3;
        }
    }
#pragma unroll
    for (int m = 0; m < NM; ++m) {
        int n2 = base + mbase + m;
        if (LAST) __builtin_nontemporal_store(acc[m], &outf[(size_t)n2 * J + j]);
        else      __builtin_nontemporal_store(f2bf(acc[m]), &outb[(size_t)n2 * J + j]);
    }
    if (!LAST && blockIdx.x == 0 && tid < 32) {
        ((uint2*)(outb + (size_t)SENT * D_H))[tid] = make_uint2(0u, 0u);
    }
}

// ======================= COOPERATIVE PATH =======================

struct Args {
    const int* src; const int* dst;
    int* coarse_cnt; unsigned* coarse;
    const float* feat;
    unsigned* hb0; unsigned* hb1; unsigned* hb2;
    const float* W0; const float* W1; const float* W2;
    unsigned* wb0; unsigned* wb1; unsigned* wb2;
    int* cnt; unsigned short* colbuf;
    float* out;
};

template <int J, bool LAST>
__device__ __forceinline__ void layer_c(const uint4* __restrict__ hb4,
                                        const int* __restrict__ cnt,
                                        const unsigned short* __restrict__ colbuf,
                                        const unsigned* __restrict__ Wb,
                                        unsigned short* outb, float* outf,
                                        float (*xs)[D_H], int b, int t) {
    const int wave = t >> 6, lane = t & 63, sub = lane >> 4, off = lane & 15;
#pragma unroll 1
    for (int it = 0; it < 4; ++it) {           // 4 x 3072 >= 10000
        const int n = it * C_NPI + b * 4 + wave;
        const bool valid = n < NN;
        const int row = valid ? n : SENT;
        float a0, a1, a2, a3, a4, a5, a6, a7;
        if (sub == 0) {
            uint4 u = hb4[row * 16 + off];
            a0 = blo(u.x); a1 = bhi(u.x); a2 = blo(u.y); a3 = bhi(u.y);
            a4 = blo(u.z); a5 = bhi(u.z); a6 = blo(u.w); a7 = bhi(u.w);
        } else {
            a0 = a1 = a2 = a3 = a4 = a5 = a6 = a7 = 0.f;
        }
        const int c = valid ? cnt[n] : 0;       // exact count; colbuf pre-filled w/ SENT
        const int iters = (c + 15) >> 4;
        const uint2* cl8 = (const uint2*)(colbuf + (size_t)row * CAP);
        for (int q = 0; q < iters; ++q) {
            const int g = q * 4;
            uint2 p0 = cl8[g + 0];
            uint2 p1 = cl8[g + 1];
            uint2 p2 = cl8[g + 2];
            uint2 p3 = cl8[g + 3];
            unsigned w0 = (sub & 2) ? p0.y : p0.x;
            unsigned w1 = (sub & 2) ? p1.y : p1.x;
            unsigned w2 = (sub & 2) ? p2.y : p2.x;
            unsigned w3 = (sub & 2) ? p3.y : p3.x;
            int s0 = (sub & 1) ? (w0 >> 16) : (w0 & 0xffffu);
            int s1 = (sub & 1) ? (w1 >> 16) : (w1 & 0xffffu);
            int s2 = (sub & 1) ? (w2 >> 16) : (w2 & 0xffffu);
            int s3 = (sub & 1) ? (w3 >> 16) : (w3 & 0xffffu);
            uint4 uA = hb4[s0 * 16 + off];
            uint4 uB = hb4[s1 * 16 + off];
            uint4 uC = hb4[s2 * 16 + off];
            uint4 uD = hb4[s3 * 16 + off];
            a0 += (blo(uA.x) + blo(uB.x)) + (blo(uC.x) + blo(uD.x));
            a1 += (bhi(uA.x) + bhi(uB.x)) + (bhi(uC.x) + bhi(uD.x));
            a2 += (blo(uA.y) + blo(uB.y)) + (blo(uC.y) + blo(uD.y));
            a3 += (bhi(uA.y) + bhi(uB.y)) + (bhi(uC.y) + bhi(uD.y));
            a4 += (blo(uA.z) + blo(uB.z)) + (blo(uC.z) + blo(uD.z));
            a5 += (bhi(uA.z) + bhi(uB.z)) + (bhi(uC.z) + bhi(uD.z));
            a6 += (blo(uA.w) + blo(uB.w)) + (blo(uC.w) + blo(uD.w));
            a7 += (bhi(uA.w) + bhi(uB.w)) + (bhi(uC.w) + bhi(uD.w));
        }
        a0 += __shfl_xor(a0, 16); a0 += __shfl_xor(a0, 32);
        a1 += __shfl_xor(a1, 16); a1 += __shfl_xor(a1, 32);
        a2 += __shfl_xor(a2, 16); a2 += __shfl_xor(a2, 32);
        a3 += __shfl_xor(a3, 16); a3 += __shfl_xor(a3, 32);
        a4 += __shfl_xor(a4, 16); a4 += __shfl_xor(a4, 32);
        a5 += __shfl_xor(a5, 16); a5 += __shfl_xor(a5, 32);
        a6 += __shfl_xor(a6, 16); a6 += __shfl_xor(a6, 32);
        a7 += __shfl_xor(a7, 16); a7 += __shfl_xor(a7, 32);
        if (sub == 0) {
            *(float4*)&xs[wave][8 * off]     = make_float4(a0, a1, a2, a3);
            *(float4*)&xs[wave][8 * off + 4] = make_float4(a4, a5, a6, a7);
        }
        __syncthreads();

        constexpr int G = 256 / J;
        constexpr int NM = 4 / G;
        const int gq = t / J;
        const int j = t % J;
        const int mbase = gq * NM;
        float acc[NM];
#pragma unroll
        for (int m = 0; m < NM; ++m) acc[m] = 0.f;
        for (int k = 0; k < D_H; k += 4) {
            unsigned wp0 = Wb[(k >> 1) * J + j];
            unsigned wp1 = Wb[((k >> 1) + 1) * J + j];
            float w0 = blo(wp0), w1 = bhi(wp0), w2 = blo(wp1), w3 = bhi(wp1);
#pragma unroll
            for (int m = 0; m < NM; ++m) {
                float4 xv = *(const float4*)&xs[mbase + m][k];
                acc[m] += xv.x * w0 + xv.y * w1 + xv.z * w2 + xv.w * w3;
            }
        }
#pragma unroll
        for (int m = 0; m < NM; ++m) {
            int n2 = it * C_NPI + b * 4 + mbase + m;
            if (n2 < NN) {
                if (LAST) __builtin_nontemporal_store(acc[m], &outf[(size_t)n2 * J + j]);
                else      __builtin_nontemporal_store(f2bf(acc[m]), &outb[(size_t)n2 * J + j]);
            }
        }
        if (!LAST && it == 0 && b == 0 && t < 32) {
            ((uint2*)(outb + (size_t)SENT * D_H))[t] = make_uint2(0u, 0u);
        }
        __syncthreads();
    }
}

__global__ __launch_bounds__(256, 4) void mega(Args a) {
    cg::grid_group grid = cg::this_grid();
    __shared__ unsigned stage[C_EPB];
    __shared__ int hist[GRP], gbase[GRP], cur[GRP];
    __shared__ float xs[4][D_H];
    const int b = blockIdx.x;
    const int t = threadIdx.x;
    const int gtid = b * C_T + t;
    const int NBT = C_NB * C_T;

    // ---- P1: coarse-bucket edges ----
    for (int i = t; i < GRP; i += C_T) hist[i] = 0;
    __syncthreads();
    const int e0 = b * C_EPB;
    const int ecnt = min(C_EPB, NE - e0);
    for (int i = t; i < ecnt; i += C_T) {
        int s = a.src[e0 + i];
        int d = a.dst[e0 + i];
        stage[i] = (unsigned)s | ((unsigned)d << 16);
        atomicAdd(&hist[d >> 6], 1);
    }
    __syncthreads();
    for (int i = t; i < GRP; i += C_T) {
        gbase[i] = atomicAdd(&a.coarse_cnt[i * CCS], hist[i]);
        cur[i] = 0;
    }
    __syncthreads();
    for (int i = t; i < ecnt; i += C_T) {
        unsigned u = stage[i];
        int g = u >> 22;
        int r = atomicAdd(&cur[g], 1);
        a.coarse[g * CAPC + gbase[g] + r] = u;
    }
    // ---- P1 aux: feature conv + W pack + cnt zero + colbuf sentinel prefill ----
    for (int i = gtid; i < (NN + 1) * 32; i += NBT) {
        if (i < NN * 32) {
            float4 f = ((const float4*)a.feat)[i];
            ((uint2*)a.hb0)[i] = make_uint2(packbf(f.x, f.y), packbf(f.z, f.w));
        } else {
            ((uint2*)a.hb0)[i] = make_uint2(0u, 0u);
        }
    }
    if (gtid < 8192) {
        int kp = gtid >> 7, j = gtid & 127;
        a.wb0[gtid] = packbf(a.W0[(2 * kp) * 128 + j], a.W0[(2 * kp + 1) * 128 + j]);
    } else if (gtid < 16384) {
        int tt = gtid - 8192, kp = tt >> 7, j = tt & 127;
        a.wb1[tt] = packbf(a.W1[(2 * kp) * 128 + j], a.W1[(2 * kp + 1) * 128 + j]);
    } else if (gtid < 20480) {
        int tt = gtid - 16384, kp = tt >> 6, j = tt & 63;
        a.wb2[tt] = packbf(a.W2[(2 * kp) * 64 + j], a.W2[(2 * kp + 1) * 64 + j]);
    }
    if (gtid < 2500) ((int4*)a.cnt)[gtid] = make_int4(0, 0, 0, 0);
    {
        const uint4 sv = make_uint4(0x27102710u, 0x27102710u, 0x27102710u, 0x27102710u);
        for (int i = gtid; i < NN * CAP / 8; i += NBT) ((uint4*)a.colbuf)[i] = sv;
    }
    __threadfence();
    grid.sync();

    // ---- P2: coarse -> per-node colbuf ----
    if (b < GRP * C_SL) {
        const int g = b / C_SL, sl = b % C_SL;
        const int m = a.coarse_cnt[g * CCS];
        const int lo = (int)((long long)m * sl / C_SL);
        const int hi = (int)((long long)m * (sl + 1) / C_SL);
        const unsigned* cb = a.coarse + g * CAPC;
        for (int i = lo + t; i < hi; i += C_T) {
            unsigned u = cb[i];
            int s = (int)(u & 0xffffu);
            int d = (int)(u >> 16);
            int r = atomicAdd(&a.cnt[d], 1);
            a.colbuf[(size_t)d * CAP + r] = (unsigned short)s;
        }
    }
    __threadfence();
    grid.sync();

    // ---- L0 / L1 / L2 ----
    layer_c<D_H, false>((const uint4*)a.hb0, a.cnt, a.colbuf, a.wb0,
                        (unsigned short*)a.hb1, nullptr, xs, b, t);
    __threadfence();
    grid.sync();
    layer_c<D_H, false>((const uint4*)a.hb1, a.cnt, a.colbuf, a.wb1,
                        (unsigned short*)a.hb2, nullptr, xs, b, t);
    __threadfence();
    grid.sync();
    layer_c<N_CLS, true>((const uint4*)a.hb2, a.cnt, a.colbuf, a.wb2,
                         nullptr, a.out, xs, b, t);
}

// ======================= LAUNCHER =======================

extern "C" void kernel_launch(void* const* d_in, const int* in_sizes, int n_in,
                              void* d_out, int out_size, void* d_ws, size_t ws_size,
                              hipStream_t stream) {
    Args a;
    a.feat = (const float*)d_in[0];
    a.W0   = (const float*)d_in[1];
    a.W1   = (const float*)d_in[2];
    a.W2   = (const float*)d_in[3];
    a.src  = (const int*)d_in[4];
    a.dst  = (const int*)d_in[5];
    a.out  = (float*)d_out;

    a.coarse_cnt = (int*)d_ws;                                    // GRP*CCS ints
    a.cnt        = a.coarse_cnt + GRP * CCS;                      // NN (+8 align pad)
    a.colbuf     = (unsigned short*)(a.cnt + NN + 8);             // NN*CAP ushorts
    a.coarse     = (unsigned*)(a.colbuf + (size_t)NN * CAP);      // GRP*CAPC
    a.hb0        = a.coarse + (size_t)GRP * CAPC;                 // (NN+1)*64
    a.hb1        = a.hb0 + (size_t)(NN + 1) * 64;
    a.hb2        = a.hb1 + (size_t)(NN + 1) * 64;
    a.wb0        = a.hb2 + (size_t)(NN + 1) * 64;                 // 8192
    a.wb1        = a.wb0 + 8192;                                  // 8192
    a.wb2        = a.wb1 + 8192;                                  // 4096

    hipMemsetAsync(a.coarse_cnt, 0, GRP * CCS * sizeof(int), stream);

    // Pre-flight: cooperative support + co-residency capacity (host queries only).
    int dev = 0;
    hipGetDevice(&dev);
    int coop = 0, ncu = 0, maxblk = 0;
    hipDeviceGetAttribute(&coop, hipDeviceAttributeCooperativeLaunch, dev);
    hipDeviceGetAttribute(&ncu, hipDeviceAttributeMultiprocessorCount, dev);
    hipOccupancyMaxActiveBlocksPerMultiprocessor(&maxblk, (const void*)mega, C_T, 0);

    if (coop && (long long)maxblk * ncu >= C_NB) {
        void* params[] = { &a };
        hipError_t e = hipLaunchCooperativeKernel((const void*)mega, dim3(C_NB), dim3(C_T),
                                                  params, 0, stream);
        if (e == hipSuccess) return;
        (void)hipGetLastError();   // clear and fall through to the proven path
    }

    // Fallback: round-9 multi-kernel pipeline (proven, 148 us).
    prep_a<<<F_AB + F_CB + F_WB, 256, 0, stream>>>(a.src, a.dst, a.coarse_cnt, a.coarse,
                                                   a.feat, a.hb0, a.W0, a.W1, a.W2,
                                                   a.wb0, a.wb1, a.wb2);
    prep_b<<<GRP, 1024, 0, stream>>>(a.coarse_cnt, a.coarse, a.cnt, a.colbuf);
    gin_layer<D_H, false><<<NN / 4, 256, 0, stream>>>((const uint4*)a.hb0, a.cnt, a.colbuf,
                                                      a.wb0, (unsigned short*)a.hb1, nullptr);
    gin_layer<D_H, false><<<NN / 4, 256, 0, stream>>>((const uint4*)a.hb1, a.cnt, a.colbuf,
                                                      a.wb1, (unsigned short*)a.hb2, nullptr);
    gin_layer<N_CLS, true><<<NN / 4, 256, 0, stream>>>((const uint4*)a.hb2, a.cnt, a.colbuf,
                                                       a.wb2, nullptr, a.out);
}

// Round 13
// 145.384 us; speedup vs baseline: 1.0442x; 1.0442x over previous
//
#include <hip/hip_runtime.h>
#include <hip/hip_bf16.h>

#define NN 10000
#define NE 640000
#define D_IN 128
#define D_H 128
#define N_CLS 64
#define CAP 160    // per-node capacity (ushort): mean 64 sigma 8 -> +12 sigma
#define GRP 157    // coarse groups: dst>>6 (64 nodes/group)
#define CAPC 4800  // per-group coarse capacity
#define CCS 16     // coarse_cnt stride (ints): one counter per 64B line
#define SENT 10000 // sentinel node id (zero row)
#define EPB 1024
#define AB 625     // 625*1024 == 640000
#define CB 1251    // (NN+1)*32 uint2 / 256
#define WB 80      // (8192+8192+4096)/256

// ---- bf16 helpers ----
__device__ __forceinline__ float blo(unsigned u) { return __uint_as_float(u << 16); }
__device__ __forceinline__ float bhi(unsigned u) { return __uint_as_float(u & 0xffff0000u); }
__device__ __forceinline__ unsigned short f2bf(float f) {
    unsigned u = __float_as_uint(f);
    return (unsigned short)((u + 0x7fffu + ((u >> 16) & 1u)) >> 16);
}
__device__ __forceinline__ unsigned packbf(float a, float b) {
    return (unsigned)f2bf(a) | ((unsigned)f2bf(b) << 16);
}

// ---- prep_a: coarse-bucket edges + f32->bf16 feature conv + W bf16 pack ----
__global__ __launch_bounds__(256) void prep_a(const int* __restrict__ src,
                                              const int* __restrict__ dst,
                                              int* __restrict__ coarse_cnt,
                                              unsigned* __restrict__ coarse,
                                              const float* __restrict__ feat,
                                              unsigned* __restrict__ hb0,
                                              const float* __restrict__ W0,
                                              const float* __restrict__ W1,
                                              const float* __restrict__ W2,
                                              unsigned* __restrict__ wb0,
                                              unsigned* __restrict__ wb1,
                                              unsigned* __restrict__ wb2) {
    int bid = blockIdx.x;
    if (bid >= AB + CB) {   // ---- W pack ----
        int t = (bid - AB - CB) * 256 + threadIdx.x;
        if (t < 8192) {
            int kp = t >> 7, j = t & 127;
            wb0[t] = packbf(W0[(2 * kp) * 128 + j], W0[(2 * kp + 1) * 128 + j]);
        } else if (t < 16384) {
            int tt = t - 8192, kp = tt >> 7, j = tt & 127;
            wb1[tt] = packbf(W1[(2 * kp) * 128 + j], W1[(2 * kp + 1) * 128 + j]);
        } else if (t < 20480) {
            int tt = t - 16384, kp = tt >> 6, j = tt & 63;
            wb2[tt] = packbf(W2[(2 * kp) * 64 + j], W2[(2 * kp + 1) * 64 + j]);
        }
        return;
    }
    if (bid >= AB) {   // ---- feature conv ----
        int t = (bid - AB) * 256 + threadIdx.x;
        if (t < NN * 32) {
            float4 f = ((const float4*)feat)[t];
            ((uint2*)hb0)[t] = make_uint2(packbf(f.x, f.y), packbf(f.z, f.w));
        } else if (t < (NN + 1) * 32) {
            ((uint2*)hb0)[t] = make_uint2(0u, 0u);
        }
        return;
    }
    __shared__ unsigned stage[EPB];
    __shared__ int hist[GRP], gbase[GRP], cur[GRP];
    const int t = threadIdx.x;
    for (int i = t; i < GRP; i += 256) hist[i] = 0;
    __syncthreads();
    const int e0 = bid * EPB;
    for (int i = t; i < EPB; i += 256) {
        int s = src[e0 + i];
        int d = dst[e0 + i];
        stage[i] = (unsigned)s | ((unsigned)d << 16);
        atomicAdd(&hist[d >> 6], 1);
    }
    __syncthreads();
    for (int i = t; i < GRP; i += 256) {
        gbase[i] = atomicAdd(&coarse_cnt[i * CCS], hist[i]);
        cur[i] = 0;
    }
    __syncthreads();
    for (int i = t; i < EPB; i += 256) {
        unsigned u = stage[i];
        int g = u >> 22;
        int r = atomicAdd(&cur[g], 1);
        coarse[g * CAPC + gbase[g] + r] = u;
    }
}

// ---- prep_b: per-group scatter into ushort colbuf + pad to x16 ----
__global__ __launch_bounds__(1024) void prep_b(const int* __restrict__ coarse_cnt,
                                               const unsigned* __restrict__ coarse,
                                               int* __restrict__ cnt,
                                               unsigned short* __restrict__ colbuf) {
    __shared__ int cur[64];
    const int g = blockIdx.x;
    const int t = threadIdx.x;
    if (t < 64) cur[t] = 0;
    __syncthreads();
    const int m = coarse_cnt[g * CCS];
    const unsigned* cb = coarse + g * CAPC;
    for (int i = t; i < m; i += 1024) {
        unsigned u = cb[i];
        int s = (int)(u & 0xFFFFu);
        int d = (int)(u >> 16);
        int r = atomicAdd(&cur[d - (g << 6)], 1);
        colbuf[d * CAP + r] = (unsigned short)s;
    }
    __syncthreads();
    if (t < 64) {
        int n = (g << 6) + t;
        if (n < NN) {
            int c = cur[t];
            int pad = (16 - (c & 15)) & 15;
            unsigned short* base = colbuf + n * CAP;
            for (int k = 0; k < pad; ++k) base[c + k] = (unsigned short)SENT;
            cnt[n] = c + pad;
        }
    }
}

// ---- fused layer: 1 node/wave, tail-free gather + (h+agg)@W(bf16) ----
template <int J, bool LAST>
__global__ __launch_bounds__(256, 4) void gin_layer(const uint4* __restrict__ hb4,
                                                    const int* __restrict__ cnt,
                                                    const unsigned short* __restrict__ colbuf,
                                                    const unsigned* __restrict__ Wb,
                                                    unsigned short* __restrict__ outb,
                                                    float* __restrict__ outf) {
    constexpr int M = 4;
    __shared__ float xs[M][D_H];
    const int base = blockIdx.x * M;
    const int tid = threadIdx.x;
    const int wave = tid >> 6;
    const int lane = tid & 63;
    const int sub = lane >> 4;
    const int off = lane & 15;

    // wave-uniform node id -> scalar (SMEM) path for count load
    const int n = __builtin_amdgcn_readfirstlane(base + wave);
    float a0, a1, a2, a3, a4, a5, a6, a7;
    if (sub == 0) {           // own row (eps=0: h + agg)
        uint4 u = hb4[n * 16 + off];
        a0 = blo(u.x); a1 = bhi(u.x); a2 = blo(u.y); a3 = bhi(u.y);
        a4 = blo(u.z); a5 = bhi(u.z); a6 = blo(u.w); a7 = bhi(u.w);
    } else {
        a0 = a1 = a2 = a3 = a4 = a5 = a6 = a7 = 0.f;
    }
    const int G4 = __builtin_amdgcn_readfirstlane(cnt[n]) >> 2;   // multiple of 4
    const uint2* cl8 = (const uint2*)(colbuf + n * CAP);
    for (int g = 0; g < G4; g += 4) {           // 16 rows in flight
        uint2 p0 = cl8[g + 0];
        uint2 p1 = cl8[g + 1];
        uint2 p2 = cl8[g + 2];
        uint2 p3 = cl8[g + 3];
        unsigned w0 = (sub & 2) ? p0.y : p0.x;
        unsigned w1 = (sub & 2) ? p1.y : p1.x;
        unsigned w2 = (sub & 2) ? p2.y : p2.x;
        unsigned w3 = (sub & 2) ? p3.y : p3.x;
        int s0 = (sub & 1) ? (w0 >> 16) : (w0 & 0xffffu);
        int s1 = (sub & 1) ? (w1 >> 16) : (w1 & 0xffffu);
        int s2 = (sub & 1) ? (w2 >> 16) : (w2 & 0xffffu);
        int s3 = (sub & 1) ? (w3 >> 16) : (w3 & 0xffffu);
        uint4 uA = hb4[s0 * 16 + off];
        uint4 uB = hb4[s1 * 16 + off];
        uint4 uC = hb4[s2 * 16 + off];
        uint4 uD = hb4[s3 * 16 + off];
        a0 += (blo(uA.x) + blo(uB.x)) + (blo(uC.x) + blo(uD.x));
        a1 += (bhi(uA.x) + bhi(uB.x)) + (bhi(uC.x) + bhi(uD.x));
        a2 += (blo(uA.y) + blo(uB.y)) + (blo(uC.y) + blo(uD.y));
        a3 += (bhi(uA.y) + bhi(uB.y)) + (bhi(uC.y) + bhi(uD.y));
        a4 += (blo(uA.z) + blo(uB.z)) + (blo(uC.z) + blo(uD.z));
        a5 += (bhi(uA.z) + bhi(uB.z)) + (bhi(uC.z) + bhi(uD.z));
        a6 += (blo(uA.w) + blo(uB.w)) + (blo(uC.w) + blo(uD.w));
        a7 += (bhi(uA.w) + bhi(uB.w)) + (bhi(uC.w) + bhi(uD.w));
    }
    a0 += __shfl_xor(a0, 16); a0 += __shfl_xor(a0, 32);
    a1 += __shfl_xor(a1, 16); a1 += __shfl_xor(a1, 32);
    a2 += __shfl_xor(a2, 16); a2 += __shfl_xor(a2, 32);
    a3 += __shfl_xor(a3, 16); a3 += __shfl_xor(a3, 32);
    a4 += __shfl_xor(a4, 16); a4 += __shfl_xor(a4, 32);
    a5 += __shfl_xor(a5, 16); a5 += __shfl_xor(a5, 32);
    a6 += __shfl_xor(a6, 16); a6 += __shfl_xor(a6, 32);
    a7 += __shfl_xor(a7, 16); a7 += __shfl_xor(a7, 32);
    if (sub == 0) {
        *(float4*)&xs[wave][8 * off]     = make_float4(a0, a1, a2, a3);
        *(float4*)&xs[wave][8 * off + 4] = make_float4(a4, a5, a6, a7);
    }
    __syncthreads();

    // ---- GEMM: W in bf16 k-pairs ----
    constexpr int G = 256 / J;
    constexpr int NM = M / G;
    const int gq = tid / J;
    const int j = tid % J;
    const int mbase = gq * NM;
    float acc[NM];
#pragma unroll
    for (int m = 0; m < NM; ++m) acc[m] = 0.f;
    for (int k = 0; k < D_H; k += 4) {
        unsigned wp0 = Wb[(k >> 1) * J + j];
        unsigned wp1 = Wb[((k >> 1) + 1) * J + j];
        float w0 = blo(wp0), w1 = bhi(wp0), w2 = blo(wp1), w3 = bhi(wp1);
#pragma unroll
        for (int m = 0; m < NM; ++m) {
            float4 xv = *(const float4*)&xs[mbase + m][k];
            acc[m] += xv.x * w0 + xv.y * w1 + xv.z * w2 + xv.w * w3;
        }
    }
#pragma unroll
    for (int m = 0; m < NM; ++m) {
        int n2 = base + mbase + m;
        if (LAST) __builtin_nontemporal_store(acc[m], &outf[(size_t)n2 * J + j]);
        else      __builtin_nontemporal_store(f2bf(acc[m]), &outb[(size_t)n2 * J + j]);
    }
    if (!LAST && blockIdx.x == 0 && tid < 32) {
        ((uint2*)(outb + (size_t)SENT * D_H))[tid] = make_uint2(0u, 0u);
    }
}

extern "C" void kernel_launch(void* const* d_in, const int* in_sizes, int n_in,
                              void* d_out, int out_size, void* d_ws, size_t ws_size,
                              hipStream_t stream) {
    const float* feat = (const float*)d_in[0];
    const float* W0   = (const float*)d_in[1];
    const float* W1   = (const float*)d_in[2];
    const float* W2   = (const float*)d_in[3];
    const int*   src  = (const int*)d_in[4];
    const int*   dst  = (const int*)d_in[5];
    float* out = (float*)d_out;

    int* coarse_cnt        = (int*)d_ws;                          // GRP*CCS ints
    int* cnt               = coarse_cnt + GRP * CCS;              // NN (+8 align pad)
    unsigned short* colbuf = (unsigned short*)(cnt + NN + 8);     // NN*CAP
    unsigned* coarse       = (unsigned*)(colbuf + (size_t)NN * CAP);  // GRP*CAPC
    unsigned* hb0          = coarse + (size_t)GRP * CAPC;         // (NN+1)*64
    unsigned* hb1          = hb0 + (size_t)(NN + 1) * 64;
    unsigned* hb2          = hb1 + (size_t)(NN + 1) * 64;
    unsigned* wb0          = hb2 + (size_t)(NN + 1) * 64;         // 8192
    unsigned* wb1          = wb0 + 8192;                          // 8192
    unsigned* wb2          = wb1 + 8192;                          // 4096

    hipMemsetAsync(coarse_cnt, 0, GRP * CCS * sizeof(int), stream);
    prep_a<<<AB + CB + WB, 256, 0, stream>>>(src, dst, coarse_cnt, coarse, feat, hb0,
                                             W0, W1, W2, wb0, wb1, wb2);
    prep_b<<<GRP, 1024, 0, stream>>>(coarse_cnt, coarse, cnt, colbuf);

    gin_layer<D_H, false><<<NN / 4, 256, 0, stream>>>((const uint4*)hb0, cnt, colbuf, wb0,
                                                      (unsigned short*)hb1, nullptr);
    gin_layer<D_H, false><<<NN / 4, 256, 0, stream>>>((const uint4*)hb1, cnt, colbuf, wb1,
                                                      (unsigned short*)hb2, nullptr);
    gin_layer<N_CLS, true><<<NN / 4, 256, 0, stream>>>((const uint4*)hb2, cnt, colbuf, wb2,
                                                       nullptr, out);
}